// Round 6
// baseline (511.847 us; speedup 1.0000x reference)
//
#include <hip/hip_runtime.h>
#include <stdint.h>

#define NB 4
#define NPTS 4096
#define MPTS 16384
#define CIN 256
#define CH0 512
#define CH1 512
#define CH2 256
#define ROWS (NB * MPTS)          // 65536
#define POS_OUT_OFF (ROWS * CH2)               // 16777216
#define BATCH_OUT_OFF (POS_OUT_OFF + ROWS * 3) // 16973824
#define CELL_CAP 40               // lambda=8, P(overflow)~1e-13

using u16 = unsigned short;
using u32 = unsigned int;

typedef __bf16 bf16x8 __attribute__((ext_vector_type(8)));
typedef float f32x4 __attribute__((ext_vector_type(4)));

__device__ __forceinline__ u16 f2bf(float f) {
  u32 u = __builtin_bit_cast(u32, f);
  u32 r = u + 0x7fffu + ((u >> 16) & 1u);   // round-to-nearest-even
  return (u16)(r >> 16);
}

// ---------------------------------------------------------------- W prep
__global__ __launch_bounds__(256) void prep_kernel(
    const float* __restrict__ W1, const float* __restrict__ W2,
    u16* __restrict__ W1T, u16* __restrict__ W2T) {
  int t = blockIdx.x * 256 + threadIdx.x;
  if (t < CH0 * CH1) {
    int n = t >> 9, k = t & 511;
    W1T[t] = f2bf(W1[k * CH1 + n]);
  } else {
    int u = t - CH0 * CH1;
    int n = u >> 9, k = u & 511;
    W2T[u] = f2bf(W2[k * CH2 + n]);
  }
}

// ---------------------------------------------------------------- tail copy
__global__ __launch_bounds__(256) void tail_kernel(
    const float* __restrict__ pos_skip, const int* __restrict__ batch_skip,
    float* __restrict__ out) {
  int t = blockIdx.x * 256 + threadIdx.x;   // 262144 total
  if (t < ROWS * 3) {
    out[POS_OUT_OFF + t] = pos_skip[t];
  } else {
    int u = t - ROWS * 3;
    out[BATCH_OUT_OFF + u] = (float)batch_skip[u];
  }
}

// ---------------------------------------------------------------- cell build
// Pack coarse points as (x,y,z,p2) [np-exact p2] and bin into 8^3 grid/batch.
__global__ __launch_bounds__(256) void build_kernel(
    const float* __restrict__ pos, float4* __restrict__ pts4,
    u32* __restrict__ cellCnt, int* __restrict__ cellIdx) {
#pragma clang fp contract(off)
  const int i = blockIdx.x * 256 + threadIdx.x;   // 64 blocks -> 16384
  const float x = pos[i * 3 + 0], y = pos[i * 3 + 1], z = pos[i * 3 + 2];
  pts4[i] = make_float4(x, y, z, (x * x + y * y) + z * z);
  const int b = i >> 12;
  int cx = (int)(x * 8.0f); cx = cx < 0 ? 0 : (cx > 7 ? 7 : cx);
  int cy = (int)(y * 8.0f); cy = cy < 0 ? 0 : (cy > 7 ? 7 : cy);
  int cz = (int)(z * 8.0f); cz = cz < 0 ? 0 : (cz > 7 ? 7 : cz);
  const int c = b * 512 + cz * 64 + cy * 8 + cx;
  const u32 slot = atomicAdd(&cellCnt[c], 1u);
  if (slot < CELL_CAP) cellIdx[c * CELL_CAP + slot] = i;   // global index
}

// ---------------------------------------------------------------- KNN (k=3)
// Spatial-hash scan. Metric is the np-exact R4 arithmetic:
//   dot = fma(qz,pz, fma(qy,py, qx*px)); tv = (q2 - 2.0f*dot) + p2
// Selection: min-3 under lexicographic (tv, idx) -- order-independent
// (atomic scatter order irrelevant) and reproduces np's index-ascending
// tie-break. Tier guarantee: +/-1 cells covers true radius 0.125; since
// |tv - d2_true| <= 4e-6, accepting requires m3 <= r^2 - 1e-5. Escalate
// to +/-2 cells (r=0.25), then full scan (never in practice).
__device__ __forceinline__ void lex_insert(float tv, int gi,
    float& m0, int& j0, float& m1, int& j1, float& m2, int& j2) {
  const bool c2 = (tv < m2) || (tv == m2 && gi < j2);
  const bool c1 = (tv < m1) || (tv == m1 && gi < j1);
  const bool c0 = (tv < m0) || (tv == m0 && gi < j0);
  const float nm2 = c2 ? (c1 ? m1 : tv) : m2;
  const int   nj2 = c2 ? (c1 ? j1 : gi) : j2;
  const float nm1 = c1 ? (c0 ? m0 : tv) : m1;
  const int   nj1 = c1 ? (c0 ? j0 : gi) : j1;
  const float nm0 = c0 ? tv : m0;
  const int   nj0 = c0 ? gi : j0;
  m2 = nm2; j2 = nj2; m1 = nm1; j1 = nj1; m0 = nm0; j0 = nj0;
}

__global__ __launch_bounds__(256) void knn_kernel(
    const float4* __restrict__ pts4, const u32* __restrict__ cellCnt,
    const int* __restrict__ cellIdx, const float* __restrict__ pos_skip,
    int* __restrict__ idx_out, float* __restrict__ w_out) {
#pragma clang fp contract(off)
  const int q = blockIdx.x * 256 + threadIdx.x;   // 256 blocks
  const int b = q >> 14;
  const float qx = pos_skip[q * 3 + 0];
  const float qy = pos_skip[q * 3 + 1];
  const float qz = pos_skip[q * 3 + 2];
  const float q2 = (qx * qx + qy * qy) + qz * qz;
  int cx = (int)(qx * 8.0f); cx = cx < 0 ? 0 : (cx > 7 ? 7 : cx);
  int cy = (int)(qy * 8.0f); cy = cy < 0 ? 0 : (cy > 7 ? 7 : cy);
  int cz = (int)(qz * 8.0f); cz = cz < 0 ? 0 : (cz > 7 ? 7 : cz);

  float m0, m1, m2;
  int j0, j1, j2;
  for (int tier = 0;; ++tier) {
    m0 = m1 = m2 = 3.4e38f;
    j0 = j1 = j2 = 0x7fffffff;
    if (tier < 2) {
      const int r = tier + 1;
      const int x0 = cx - r < 0 ? 0 : cx - r, x1 = cx + r > 7 ? 7 : cx + r;
      const int y0 = cy - r < 0 ? 0 : cy - r, y1 = cy + r > 7 ? 7 : cy + r;
      const int z0 = cz - r < 0 ? 0 : cz - r, z1 = cz + r > 7 ? 7 : cz + r;
      for (int nz = z0; nz <= z1; ++nz) {
        for (int ny = y0; ny <= y1; ++ny) {
          for (int nx = x0; nx <= x1; ++nx) {
            const int c = b * 512 + nz * 64 + ny * 8 + nx;
            u32 cnt = cellCnt[c];
            if (cnt > CELL_CAP) cnt = CELL_CAP;
            const int* cl = cellIdx + c * CELL_CAP;
            for (u32 s = 0; s < cnt; ++s) {
              const int gi = cl[s];
              const float4 p = pts4[gi];
              const float dot = fmaf(qz, p.z, fmaf(qy, p.y, qx * p.x));
              const float tv = (q2 - 2.0f * dot) + p.w;
              lex_insert(tv, gi, m0, j0, m1, j1, m2, j2);
            }
          }
        }
      }
      const float thr = (tier == 0) ? (0.015625f - 1e-5f) : (0.0625f - 1e-5f);
      if (m2 <= thr) break;
    } else {
      const int base = b * NPTS;
      for (int k = 0; k < NPTS; ++k) {
        const int gi = base + k;
        const float4 p = pts4[gi];
        const float dot = fmaf(qz, p.z, fmaf(qy, p.y, qx * p.x));
        const float tv = (q2 - 2.0f * dot) + p.w;
        lex_insert(tv, gi, m0, j0, m1, j1, m2, j2);
      }
      break;
    }
  }

  const float w0 = 1.0f / fmaxf(m0, 1e-16f);
  const float w1 = 1.0f / fmaxf(m1, 1e-16f);
  const float w2 = 1.0f / fmaxf(m2, 1e-16f);
  const float wsum = (w0 + w1) + w2;
  const float inv = 1.0f / wsum;
  idx_out[q * 3 + 0] = j0;
  idx_out[q * 3 + 1] = j1;
  idx_out[q * 3 + 2] = j2;
  w_out[q * 3 + 0] = w0 * inv;
  w_out[q * 3 + 1] = w1 * inv;
  w_out[q * 3 + 2] = w2 * inv;
}

// ---------------------------------------------------------------- interp + concat -> bf16
__global__ __launch_bounds__(256) void interp_kernel(
    const float* __restrict__ x, const int* __restrict__ idx,
    const float* __restrict__ w, const float* __restrict__ x_skip,
    u16* __restrict__ H) {
  const int row = blockIdx.x * 4 + (threadIdx.x >> 6);
  const int lane = threadIdx.x & 63;
  const int i0 = idx[row * 3 + 0], i1 = idx[row * 3 + 1], i2 = idx[row * 3 + 2];
  const float w0 = w[row * 3 + 0], w1 = w[row * 3 + 1], w2 = w[row * 3 + 2];
  const float4 a0 = ((const float4*)(x + (size_t)i0 * CIN))[lane];
  const float4 a1 = ((const float4*)(x + (size_t)i1 * CIN))[lane];
  const float4 a2 = ((const float4*)(x + (size_t)i2 * CIN))[lane];
  const float4 s  = ((const float4*)(x_skip + (size_t)row * CIN))[lane];
  float y0 = fmaf(w0, a0.x, fmaf(w1, a1.x, w2 * a2.x));
  float y1 = fmaf(w0, a0.y, fmaf(w1, a1.y, w2 * a2.y));
  float y2 = fmaf(w0, a0.z, fmaf(w1, a1.z, w2 * a2.z));
  float y3 = fmaf(w0, a0.w, fmaf(w1, a1.w, w2 * a2.w));
  u16* rp = H + (size_t)row * CH0;
  u32 lo = (u32)f2bf(y0) | ((u32)f2bf(y1) << 16);
  u32 hi = (u32)f2bf(y2) | ((u32)f2bf(y3) << 16);
  *(uint2*)(rp + lane * 4) = make_uint2(lo, hi);
  lo = (u32)f2bf(s.x) | ((u32)f2bf(s.y) << 16);
  hi = (u32)f2bf(s.z) | ((u32)f2bf(s.w) << 16);
  *(uint2*)(rp + CIN + lane * 4) = make_uint2(lo, hi);
}

// ---------------------------------------------------------------- GEMM (m97-style)
__device__ __forceinline__ void gload_lds16(const u16* g, u16* l) {
  __builtin_amdgcn_global_load_lds(
      (__attribute__((address_space(1))) void*)g,
      (__attribute__((address_space(3))) void*)l, 16, 0, 0);
}

template <int KD, int ND, bool OUT_BF16>
__global__ __launch_bounds__(256) void gemm_kernel(
    const u16* __restrict__ A, const u16* __restrict__ Bt,
    const float* __restrict__ bias, void* __restrict__ Cout) {
  __shared__ __align__(16) u16 As[128 * 32];
  __shared__ __align__(16) u16 Bs[128 * 32];
  const int wid = threadIdx.x >> 6;
  const int lane = threadIdx.x & 63;
  const size_t arow0 = (size_t)blockIdx.x * 128;
  const size_t brow0 = (size_t)blockIdx.y * 128;
  const int c0 = wid * 2, c1 = wid * 2 + 1;
  const int lr = lane >> 2;
  const int lk = (lane & 3) * 8;
  const u16* gA0 = A + (arow0 + c0 * 16 + lr) * KD + lk;
  const u16* gA1 = A + (arow0 + c1 * 16 + lr) * KD + lk;
  const u16* gB0 = Bt + (brow0 + c0 * 16 + lr) * KD + lk;
  const u16* gB1 = Bt + (brow0 + c1 * 16 + lr) * KD + lk;
  u16* lA0 = As + c0 * 512 + lane * 8;
  u16* lA1 = As + c1 * 512 + lane * 8;
  u16* lB0 = Bs + c0 * 512 + lane * 8;
  u16* lB1 = Bs + c1 * 512 + lane * 8;

  f32x4 acc[4][4];
#pragma unroll
  for (int mi = 0; mi < 4; mi++)
#pragma unroll
    for (int ni = 0; ni < 4; ni++) acc[mi][ni] = (f32x4){0.f, 0.f, 0.f, 0.f};

  const int wr = (wid >> 1) * 64;
  const int wc = (wid & 1) * 64;
  const int fr = lane & 15;
  const int fk = (lane >> 4) * 8;

  for (int k0 = 0; k0 < KD; k0 += 32) {
    gload_lds16(gA0 + k0, lA0);
    gload_lds16(gA1 + k0, lA1);
    gload_lds16(gB0 + k0, lB0);
    gload_lds16(gB1 + k0, lB1);
    __syncthreads();
    bf16x8 af[4], bfr[4];
#pragma unroll
    for (int mi = 0; mi < 4; mi++)
      af[mi] = *(const bf16x8*)&As[(wr + mi * 16 + fr) * 32 + fk];
#pragma unroll
    for (int ni = 0; ni < 4; ni++)
      bfr[ni] = *(const bf16x8*)&Bs[(wc + ni * 16 + fr) * 32 + fk];
#pragma unroll
    for (int mi = 0; mi < 4; mi++)
#pragma unroll
      for (int ni = 0; ni < 4; ni++)
        acc[mi][ni] = __builtin_amdgcn_mfma_f32_16x16x32_bf16(
            af[mi], bfr[ni], acc[mi][ni], 0, 0, 0);
    __syncthreads();
  }

  const int rbase = (int)arow0 + wr + (lane >> 4) * 4;
  const int cbase = (int)brow0 + wc + fr;
#pragma unroll
  for (int ni = 0; ni < 4; ni++) {
    const int colg = cbase + ni * 16;
    const float bc = bias[colg];
#pragma unroll
    for (int mi = 0; mi < 4; mi++) {
#pragma unroll
      for (int r = 0; r < 4; r++) {
        float v = fmaxf(acc[mi][ni][r] + bc, 0.f);
        const size_t o = (size_t)(rbase + mi * 16 + r) * ND + colg;
        if constexpr (OUT_BF16) ((u16*)Cout)[o] = f2bf(v);
        else                    ((float*)Cout)[o] = v;
      }
    }
  }
}

// ---------------------------------------------------------------- launch
extern "C" void kernel_launch(void* const* d_in, const int* in_sizes, int n_in,
                              void* d_out, int out_size, void* d_ws, size_t ws_size,
                              hipStream_t stream) {
  const float* x        = (const float*)d_in[0];
  const float* pos      = (const float*)d_in[1];
  const float* x_skip   = (const float*)d_in[3];
  const float* pos_skip = (const float*)d_in[4];
  const int*   batch_sk = (const int*)d_in[5];
  const float* W1       = (const float*)d_in[6];
  const float* b1       = (const float*)d_in[7];
  const float* W2       = (const float*)d_in[8];
  const float* b2       = (const float*)d_in[9];
  float* out = (float*)d_out;

  char* ws = (char*)d_ws;
  u16*   W1T  = (u16*)(ws);                    // 524288 B
  u16*   W2T  = (u16*)(ws + 524288);           // 262144 B
  int*   idxb = (int*)(ws + 786432);           // 786432 B
  float* wb   = (float*)(ws + 1572864);        // 786432 B
  u16*   Hcat = (u16*)(ws + 2359296);          // 67108864 B  [65536,512] bf16
  u16*   H1   = (u16*)(ws + 69468160);         // 67108864 B  [65536,512] bf16
  // KNN scratch aliases the TAIL of H1 (total ws footprint unchanged):
  // build/knn complete before gemm1 (the writer of H1) launches on stream.
  float4* pts4    = (float4*)(ws + 132382720); // 262144 B
  u32*    cellCnt = (u32*)(ws + 132644864);    // 8192 B   (4*512 cells)
  int*    cellIdx = (int*)(ws + 132653056);    // 327680 B (2048*CELL_CAP*4)
  // ends 132980736 < 136577024 (H1 end)

  hipMemsetAsync(cellCnt, 0, 4 * 512 * sizeof(u32), stream);
  prep_kernel<<<dim3(1536), dim3(256), 0, stream>>>(W1, W2, W1T, W2T);
  tail_kernel<<<dim3(1024), dim3(256), 0, stream>>>(pos_skip, batch_sk, out);
  build_kernel<<<dim3(64), dim3(256), 0, stream>>>(pos, pts4, cellCnt, cellIdx);
  knn_kernel<<<dim3(256), dim3(256), 0, stream>>>(pts4, cellCnt, cellIdx,
                                                  pos_skip, idxb, wb);
  interp_kernel<<<dim3(16384), dim3(256), 0, stream>>>(x, idxb, wb, x_skip, Hcat);
  gemm_kernel<CH0, CH1, true><<<dim3(ROWS / 128, CH1 / 128), dim3(256), 0, stream>>>(
      Hcat, W1T, b1, (void*)H1);
  gemm_kernel<CH1, CH2, false><<<dim3(ROWS / 128, CH2 / 128), dim3(256), 0, stream>>>(
      H1, W2T, b2, (void*)out);
}

// Round 7
// 299.517 us; speedup vs baseline: 1.7089x; 1.7089x over previous
//
#include <hip/hip_runtime.h>
#include <stdint.h>

#define NB 4
#define NPTS 4096
#define MPTS 16384
#define CIN 256
#define CH0 512
#define CH1 512
#define CH2 256
#define ROWS (NB * MPTS)          // 65536
#define POS_OUT_OFF (ROWS * CH2)               // 16777216
#define BATCH_OUT_OFF (POS_OUT_OFF + ROWS * 3) // 16973824
#define CELL_CAP 40               // lambda=8/cell, P(overflow)~1e-13
#define QCAP 96                   // lambda=32/cell, P(overflow)~1e-20

using u16 = unsigned short;
using u32 = unsigned int;
using u64 = unsigned long long;

typedef __bf16 bf16x8 __attribute__((ext_vector_type(8)));
typedef float f32x4 __attribute__((ext_vector_type(4)));

__device__ __forceinline__ u16 f2bf(float f) {
  u32 u = __builtin_bit_cast(u32, f);
  u32 r = u + 0x7fffu + ((u >> 16) & 1u);   // round-to-nearest-even
  return (u16)(r >> 16);
}

// monotone f32 -> u32 order-preserving map (handles negatives)
__device__ __forceinline__ u32 flipf(float f) {
  u32 u = __builtin_bit_cast(u32, f);
  return u ^ ((u32)((int)u >> 31) | 0x80000000u);
}
__device__ __forceinline__ float unflipf(u32 f) {
  u32 m = (~(u32)((int)f >> 31)) | 0x80000000u;
  return __builtin_bit_cast(float, f ^ m);
}

// insert v into sorted triple k0<=k1<=k2 (v not a duplicate of any ki)
__device__ __forceinline__ void ins3(u64 v, u64& k0, u64& k1, u64& k2) {
  u64 a = k0 < v ? v : k0;
  k0 = k0 < v ? k0 : v;
  u64 bb = k1 < a ? a : k1;
  k1 = k1 < a ? k1 : a;
  k2 = k2 < bb ? k2 : bb;
}

// merge remote sorted triple into local sorted triple (disjoint sets)
__device__ __forceinline__ void merge3(u64 r0, u64 r1, u64 r2,
                                       u64& k0, u64& k1, u64& k2) {
  u64 t = k0 < r0 ? r0 : k0;
  k0 = k0 < r0 ? k0 : r0;
  u64 u = k1 < r1 ? k1 : r1;
  u64 mtu = t < u ? u : t;
  k1 = t < u ? t : u;
  u64 v = k2 < r2 ? k2 : r2;
  k2 = mtu < v ? mtu : v;
}

__device__ __forceinline__ u64 shfl_xor_u64_w8(u64 v, int mask) {
  u32 lo = (u32)v, hi = (u32)(v >> 32);
  lo = (u32)__shfl_xor((int)lo, mask, 8);
  hi = (u32)__shfl_xor((int)hi, mask, 8);
  return ((u64)hi << 32) | lo;
}

// ---------------------------------------------------------------- W prep
__global__ __launch_bounds__(256) void prep_kernel(
    const float* __restrict__ W1, const float* __restrict__ W2,
    u16* __restrict__ W1T, u16* __restrict__ W2T) {
  int t = blockIdx.x * 256 + threadIdx.x;
  if (t < CH0 * CH1) {
    int n = t >> 9, k = t & 511;
    W1T[t] = f2bf(W1[k * CH1 + n]);
  } else {
    int u = t - CH0 * CH1;
    int n = u >> 9, k = u & 511;
    W2T[u] = f2bf(W2[k * CH2 + n]);
  }
}

// ---------------------------------------------------------------- tail copy
__global__ __launch_bounds__(256) void tail_kernel(
    const float* __restrict__ pos_skip, const int* __restrict__ batch_skip,
    float* __restrict__ out) {
  int t = blockIdx.x * 256 + threadIdx.x;   // 262144 total
  if (t < ROWS * 3) {
    out[POS_OUT_OFF + t] = pos_skip[t];
  } else {
    int u = t - ROWS * 3;
    out[BATCH_OUT_OFF + u] = (float)batch_skip[u];
  }
}

// ---------------------------------------------------------------- cell build
__global__ __launch_bounds__(256) void build_kernel(
    const float* __restrict__ pos, float4* __restrict__ pts4,
    u32* __restrict__ cellCnt, int* __restrict__ cellIdx) {
#pragma clang fp contract(off)
  const int i = blockIdx.x * 256 + threadIdx.x;   // 64 blocks -> 16384
  const float x = pos[i * 3 + 0], y = pos[i * 3 + 1], z = pos[i * 3 + 2];
  pts4[i] = make_float4(x, y, z, (x * x + y * y) + z * z);
  const int b = i >> 12;
  int cx = (int)(x * 8.0f); cx = cx < 0 ? 0 : (cx > 7 ? 7 : cx);
  int cy = (int)(y * 8.0f); cy = cy < 0 ? 0 : (cy > 7 ? 7 : cy);
  int cz = (int)(z * 8.0f); cz = cz < 0 ? 0 : (cz > 7 ? 7 : cz);
  const int c = b * 512 + cz * 64 + cy * 8 + cx;
  const u32 slot = atomicAdd(&cellCnt[c], 1u);
  if (slot < CELL_CAP) cellIdx[c * CELL_CAP + slot] = i;   // global index
}

// ---------------------------------------------------------------- query bin
__global__ __launch_bounds__(256) void qbin_kernel(
    const float* __restrict__ pos_skip, u32* __restrict__ qCnt,
    int* __restrict__ qIdx) {
  const int q = blockIdx.x * 256 + threadIdx.x;   // 256 blocks -> 65536
  const int b = q >> 14;
  const float qx = pos_skip[q * 3 + 0];
  const float qy = pos_skip[q * 3 + 1];
  const float qz = pos_skip[q * 3 + 2];
  int cx = (int)(qx * 8.0f); cx = cx < 0 ? 0 : (cx > 7 ? 7 : cx);
  int cy = (int)(qy * 8.0f); cy = cy < 0 ? 0 : (cy > 7 ? 7 : cy);
  int cz = (int)(qz * 8.0f); cz = cz < 0 ? 0 : (cz > 7 ? 7 : cz);
  const int c = b * 512 + cz * 64 + cy * 8 + cx;
  const u32 slot = atomicAdd(&qCnt[c], 1u);
  if (slot < QCAP) qIdx[c * QCAP + slot] = q;
}

// ---------------------------------------------------------------- KNN (k=3)
// One block per (batch, cell). Stage <=27 neighbor cells' points into LDS,
// then 8 lanes per query scan the LDS list; shuffle-merge top-3.
// Metric: np-exact R4 arithmetic. Order: u64 (flipped tv, idx) -- identical
// semantics to R6's validated lexicographic (tv, idx).
// Escalation (same thresholds as R6): +/-2 global rescan, then full scan.
__global__ __launch_bounds__(256) void knn_kernel(
    const float4* __restrict__ pts4, const u32* __restrict__ cellCnt,
    const int* __restrict__ cellIdx, const u32* __restrict__ qCnt,
    const int* __restrict__ qIdx, const float* __restrict__ pos_skip,
    int* __restrict__ idx_out, float* __restrict__ w_out) {
#pragma clang fp contract(off)
  __shared__ float4 scand[27 * CELL_CAP];
  __shared__ int    scgi[27 * CELL_CAP];
  __shared__ u32    scnt[27];
  __shared__ int    sbase[27];
  __shared__ u32    nCand;
  const int tid = threadIdx.x;
  const int b = blockIdx.x >> 9;
  const int cell = blockIdx.x & 511;
  const int cz = cell >> 6, cy = (cell >> 3) & 7, cx = cell & 7;
  const int x0 = cx > 0 ? cx - 1 : 0, x1 = cx < 7 ? cx + 1 : 7;
  const int y0 = cy > 0 ? cy - 1 : 0, y1 = cy < 7 ? cy + 1 : 7;
  const int z0 = cz > 0 ? cz - 1 : 0, z1 = cz < 7 ? cz + 1 : 7;
  const int nx = x1 - x0 + 1, ny = y1 - y0 + 1, nz = z1 - z0 + 1;
  const int ncells = nx * ny * nz;
  if (tid == 0) nCand = 0;
  if (tid < ncells) {
    const int lz = tid / (nx * ny);
    const int rem = tid - lz * nx * ny;
    const int ly = rem / nx;
    const int lx = rem - ly * nx;
    const int cg = b * 512 + (z0 + lz) * 64 + (y0 + ly) * 8 + (x0 + lx);
    u32 cnt = cellCnt[cg];
    scnt[tid] = cnt > CELL_CAP ? CELL_CAP : cnt;
    sbase[tid] = cg * CELL_CAP;
  }
  __syncthreads();
  const int slots = ncells * CELL_CAP;
  for (int s = tid; s < slots; s += 256) {
    const int ci = s / CELL_CAP;
    const int sl = s - ci * CELL_CAP;
    if ((u32)sl < scnt[ci]) {
      const int gi = cellIdx[sbase[ci] + sl];
      const float4 p = pts4[gi];
      const u32 d = atomicAdd(&nCand, 1u);
      scand[d] = p;
      scgi[d] = gi;
    }
  }
  __syncthreads();
  const int nC = (int)nCand;
  u32 nq = qCnt[b * 512 + cell];
  if (nq > QCAP) nq = QCAP;
  const int qbase = (b * 512 + cell) * QCAP;
  const int g = tid >> 3;       // query-group 0..31
  const int sub = tid & 7;      // lane within group

  for (int r0q = 0; r0q < (int)nq; r0q += 32) {
    const int qslot = r0q + g;
    if (qslot < (int)nq) {
      const int q = qIdx[qbase + qslot];
      const float qx = pos_skip[q * 3 + 0];
      const float qy = pos_skip[q * 3 + 1];
      const float qz = pos_skip[q * 3 + 2];
      const float q2 = (qx * qx + qy * qy) + qz * qz;
      u64 k0 = ~0ull, k1 = ~0ull, k2 = ~0ull;
      for (int s = sub; s < nC; s += 8) {
        const float4 p = scand[s];
        const float dot = fmaf(qz, p.z, fmaf(qy, p.y, qx * p.x));
        const float tv = (q2 - 2.0f * dot) + p.w;
        const u64 key = ((u64)flipf(tv) << 32) | (u32)scgi[s];
        ins3(key, k0, k1, k2);
      }
#pragma unroll
      for (int mask = 1; mask < 8; mask <<= 1) {
        const u64 r0 = shfl_xor_u64_w8(k0, mask);
        const u64 r1 = shfl_xor_u64_w8(k1, mask);
        const u64 r2 = shfl_xor_u64_w8(k2, mask);
        merge3(r0, r1, r2, k0, k1, k2);
      }
      float m2tv = unflipf((u32)(k2 >> 32));
      // NaN (unfilled slot) compares false -> escalate. +/-1 covers r=0.125.
      if (!(m2tv <= 0.015625f - 1e-5f)) {
        // tier +/-2 (covers r=0.25), fresh restart, global gather
        k0 = k1 = k2 = ~0ull;
        const int ex0 = cx > 1 ? cx - 2 : 0, ex1 = cx < 6 ? cx + 2 : 7;
        const int ey0 = cy > 1 ? cy - 2 : 0, ey1 = cy < 6 ? cy + 2 : 7;
        const int ez0 = cz > 1 ? cz - 2 : 0, ez1 = cz < 6 ? cz + 2 : 7;
        for (int zz = ez0; zz <= ez1; ++zz)
          for (int yy = ey0; yy <= ey1; ++yy)
            for (int xx = ex0; xx <= ex1; ++xx) {
              const int cg = b * 512 + zz * 64 + yy * 8 + xx;
              u32 cnt = cellCnt[cg];
              if (cnt > CELL_CAP) cnt = CELL_CAP;
              const int cb = cg * CELL_CAP;
              for (int s = sub; s < (int)cnt; s += 8) {
                const int gi = cellIdx[cb + s];
                const float4 p = pts4[gi];
                const float dot = fmaf(qz, p.z, fmaf(qy, p.y, qx * p.x));
                const float tv = (q2 - 2.0f * dot) + p.w;
                ins3(((u64)flipf(tv) << 32) | (u32)gi, k0, k1, k2);
              }
            }
#pragma unroll
        for (int mask = 1; mask < 8; mask <<= 1) {
          const u64 r0 = shfl_xor_u64_w8(k0, mask);
          const u64 r1 = shfl_xor_u64_w8(k1, mask);
          const u64 r2 = shfl_xor_u64_w8(k2, mask);
          merge3(r0, r1, r2, k0, k1, k2);
        }
        m2tv = unflipf((u32)(k2 >> 32));
        if (!(m2tv <= 0.0625f - 1e-5f)) {
          // full scan (provably exact; ~never taken)
          k0 = k1 = k2 = ~0ull;
          const int base = b * NPTS;
          for (int i = sub; i < NPTS; i += 8) {
            const int gi = base + i;
            const float4 p = pts4[gi];
            const float dot = fmaf(qz, p.z, fmaf(qy, p.y, qx * p.x));
            const float tv = (q2 - 2.0f * dot) + p.w;
            ins3(((u64)flipf(tv) << 32) | (u32)gi, k0, k1, k2);
          }
#pragma unroll
          for (int mask = 1; mask < 8; mask <<= 1) {
            const u64 r0 = shfl_xor_u64_w8(k0, mask);
            const u64 r1 = shfl_xor_u64_w8(k1, mask);
            const u64 r2 = shfl_xor_u64_w8(k2, mask);
            merge3(r0, r1, r2, k0, k1, k2);
          }
        }
      }
      if (sub == 0) {
        const float t0 = unflipf((u32)(k0 >> 32));
        const float t1 = unflipf((u32)(k1 >> 32));
        const float t2 = unflipf((u32)(k2 >> 32));
        const int j0 = (int)(u32)k0;
        const int j1 = (int)(u32)k1;
        const int j2 = (int)(u32)k2;
        const float w0 = 1.0f / fmaxf(t0, 1e-16f);
        const float w1 = 1.0f / fmaxf(t1, 1e-16f);
        const float w2 = 1.0f / fmaxf(t2, 1e-16f);
        const float wsum = (w0 + w1) + w2;
        const float inv = 1.0f / wsum;
        idx_out[q * 3 + 0] = j0;
        idx_out[q * 3 + 1] = j1;
        idx_out[q * 3 + 2] = j2;
        w_out[q * 3 + 0] = w0 * inv;
        w_out[q * 3 + 1] = w1 * inv;
        w_out[q * 3 + 2] = w2 * inv;
      }
    }
  }
}

// ---------------------------------------------------------------- interp + concat -> bf16
__global__ __launch_bounds__(256) void interp_kernel(
    const float* __restrict__ x, const int* __restrict__ idx,
    const float* __restrict__ w, const float* __restrict__ x_skip,
    u16* __restrict__ H) {
  const int row = blockIdx.x * 4 + (threadIdx.x >> 6);
  const int lane = threadIdx.x & 63;
  const int i0 = idx[row * 3 + 0], i1 = idx[row * 3 + 1], i2 = idx[row * 3 + 2];
  const float w0 = w[row * 3 + 0], w1 = w[row * 3 + 1], w2 = w[row * 3 + 2];
  const float4 a0 = ((const float4*)(x + (size_t)i0 * CIN))[lane];
  const float4 a1 = ((const float4*)(x + (size_t)i1 * CIN))[lane];
  const float4 a2 = ((const float4*)(x + (size_t)i2 * CIN))[lane];
  const float4 s  = ((const float4*)(x_skip + (size_t)row * CIN))[lane];
  float y0 = fmaf(w0, a0.x, fmaf(w1, a1.x, w2 * a2.x));
  float y1 = fmaf(w0, a0.y, fmaf(w1, a1.y, w2 * a2.y));
  float y2 = fmaf(w0, a0.z, fmaf(w1, a1.z, w2 * a2.z));
  float y3 = fmaf(w0, a0.w, fmaf(w1, a1.w, w2 * a2.w));
  u16* rp = H + (size_t)row * CH0;
  u32 lo = (u32)f2bf(y0) | ((u32)f2bf(y1) << 16);
  u32 hi = (u32)f2bf(y2) | ((u32)f2bf(y3) << 16);
  *(uint2*)(rp + lane * 4) = make_uint2(lo, hi);
  lo = (u32)f2bf(s.x) | ((u32)f2bf(s.y) << 16);
  hi = (u32)f2bf(s.z) | ((u32)f2bf(s.w) << 16);
  *(uint2*)(rp + CIN + lane * 4) = make_uint2(lo, hi);
}

// ---------------------------------------------------------------- GEMM (m97-style)
__device__ __forceinline__ void gload_lds16(const u16* g, u16* l) {
  __builtin_amdgcn_global_load_lds(
      (__attribute__((address_space(1))) void*)g,
      (__attribute__((address_space(3))) void*)l, 16, 0, 0);
}

template <int KD, int ND, bool OUT_BF16>
__global__ __launch_bounds__(256) void gemm_kernel(
    const u16* __restrict__ A, const u16* __restrict__ Bt,
    const float* __restrict__ bias, void* __restrict__ Cout) {
  __shared__ __align__(16) u16 As[128 * 32];
  __shared__ __align__(16) u16 Bs[128 * 32];
  const int wid = threadIdx.x >> 6;
  const int lane = threadIdx.x & 63;
  const size_t arow0 = (size_t)blockIdx.x * 128;
  const size_t brow0 = (size_t)blockIdx.y * 128;
  const int c0 = wid * 2, c1 = wid * 2 + 1;
  const int lr = lane >> 2;
  const int lk = (lane & 3) * 8;
  const u16* gA0 = A + (arow0 + c0 * 16 + lr) * KD + lk;
  const u16* gA1 = A + (arow0 + c1 * 16 + lr) * KD + lk;
  const u16* gB0 = Bt + (brow0 + c0 * 16 + lr) * KD + lk;
  const u16* gB1 = Bt + (brow0 + c1 * 16 + lr) * KD + lk;
  u16* lA0 = As + c0 * 512 + lane * 8;
  u16* lA1 = As + c1 * 512 + lane * 8;
  u16* lB0 = Bs + c0 * 512 + lane * 8;
  u16* lB1 = Bs + c1 * 512 + lane * 8;

  f32x4 acc[4][4];
#pragma unroll
  for (int mi = 0; mi < 4; mi++)
#pragma unroll
    for (int ni = 0; ni < 4; ni++) acc[mi][ni] = (f32x4){0.f, 0.f, 0.f, 0.f};

  const int wr = (wid >> 1) * 64;
  const int wc = (wid & 1) * 64;
  const int fr = lane & 15;
  const int fk = (lane >> 4) * 8;

  for (int k0 = 0; k0 < KD; k0 += 32) {
    gload_lds16(gA0 + k0, lA0);
    gload_lds16(gA1 + k0, lA1);
    gload_lds16(gB0 + k0, lB0);
    gload_lds16(gB1 + k0, lB1);
    __syncthreads();
    bf16x8 af[4], bfr[4];
#pragma unroll
    for (int mi = 0; mi < 4; mi++)
      af[mi] = *(const bf16x8*)&As[(wr + mi * 16 + fr) * 32 + fk];
#pragma unroll
    for (int ni = 0; ni < 4; ni++)
      bfr[ni] = *(const bf16x8*)&Bs[(wc + ni * 16 + fr) * 32 + fk];
#pragma unroll
    for (int mi = 0; mi < 4; mi++)
#pragma unroll
      for (int ni = 0; ni < 4; ni++)
        acc[mi][ni] = __builtin_amdgcn_mfma_f32_16x16x32_bf16(
            af[mi], bfr[ni], acc[mi][ni], 0, 0, 0);
    __syncthreads();
  }

  const int rbase = (int)arow0 + wr + (lane >> 4) * 4;
  const int cbase = (int)brow0 + wc + fr;
#pragma unroll
  for (int ni = 0; ni < 4; ni++) {
    const int colg = cbase + ni * 16;
    const float bc = bias[colg];
#pragma unroll
    for (int mi = 0; mi < 4; mi++) {
#pragma unroll
      for (int r = 0; r < 4; r++) {
        float v = fmaxf(acc[mi][ni][r] + bc, 0.f);
        const size_t o = (size_t)(rbase + mi * 16 + r) * ND + colg;
        if constexpr (OUT_BF16) ((u16*)Cout)[o] = f2bf(v);
        else                    ((float*)Cout)[o] = v;
      }
    }
  }
}

// ---------------------------------------------------------------- launch
extern "C" void kernel_launch(void* const* d_in, const int* in_sizes, int n_in,
                              void* d_out, int out_size, void* d_ws, size_t ws_size,
                              hipStream_t stream) {
  const float* x        = (const float*)d_in[0];
  const float* pos      = (const float*)d_in[1];
  const float* x_skip   = (const float*)d_in[3];
  const float* pos_skip = (const float*)d_in[4];
  const int*   batch_sk = (const int*)d_in[5];
  const float* W1       = (const float*)d_in[6];
  const float* b1       = (const float*)d_in[7];
  const float* W2       = (const float*)d_in[8];
  const float* b2       = (const float*)d_in[9];
  float* out = (float*)d_out;

  char* ws = (char*)d_ws;
  u16*   W1T  = (u16*)(ws);                    // 524288 B
  u16*   W2T  = (u16*)(ws + 524288);           // 262144 B
  int*   idxb = (int*)(ws + 786432);           // 786432 B
  float* wb   = (float*)(ws + 1572864);        // 786432 B
  u16*   Hcat = (u16*)(ws + 2359296);          // 67108864 B  [65536,512] bf16
  u16*   H1   = (u16*)(ws + 69468160);         // 67108864 B  [65536,512] bf16
  // KNN scratch aliases the TAIL of H1 (stream-ordered: knn completes
  // before gemm1, the writer of H1, launches).
  float4* pts4    = (float4*)(ws + 132382720); // 262144 B
  u32*    cellCnt = (u32*)(ws + 132644864);    // 8192 B (2048 cells)
  u32*    qCnt    = (u32*)(ws + 132653056);    // 8192 B
  int*    cellIdx = (int*)(ws + 132661248);    // 327680 B (2048*40*4)
  int*    qIdx    = (int*)(ws + 132988928);    // 786432 B (2048*96*4)
  // ends 133775360 < 136577024 (H1 end)

  hipMemsetAsync(cellCnt, 0, 16384, stream);   // cellCnt + qCnt
  prep_kernel<<<dim3(1536), dim3(256), 0, stream>>>(W1, W2, W1T, W2T);
  tail_kernel<<<dim3(1024), dim3(256), 0, stream>>>(pos_skip, batch_sk, out);
  build_kernel<<<dim3(64), dim3(256), 0, stream>>>(pos, pts4, cellCnt, cellIdx);
  qbin_kernel<<<dim3(256), dim3(256), 0, stream>>>(pos_skip, qCnt, qIdx);
  knn_kernel<<<dim3(2048), dim3(256), 0, stream>>>(pts4, cellCnt, cellIdx,
                                                   qCnt, qIdx, pos_skip,
                                                   idxb, wb);
  interp_kernel<<<dim3(16384), dim3(256), 0, stream>>>(x, idxb, wb, x_skip, Hcat);
  gemm_kernel<CH0, CH1, true><<<dim3(ROWS / 128, CH1 / 128), dim3(256), 0, stream>>>(
      Hcat, W1T, b1, (void*)H1);
  gemm_kernel<CH1, CH2, false><<<dim3(ROWS / 128, CH2 / 128), dim3(256), 0, stream>>>(
      H1, W2T, b2, (void*)out);
}

// Round 9
// 271.996 us; speedup vs baseline: 1.8818x; 1.1012x over previous
//
#include <hip/hip_runtime.h>
#include <stdint.h>

#define NB 4
#define NPTS 4096
#define MPTS 16384
#define CIN 256
#define CH0 512
#define CH1 512
#define CH2 256
#define ROWS (NB * MPTS)          // 65536
#define POS_OUT_OFF (ROWS * CH2)               // 16777216
#define BATCH_OUT_OFF (POS_OUT_OFF + ROWS * 3) // 16973824
#define CELL_CAP 40               // lambda=8/cell
#define QCAP 96                   // lambda=32/cell

using u16 = unsigned short;
using u32 = unsigned int;
using u64 = unsigned long long;

typedef __bf16 bf16x8 __attribute__((ext_vector_type(8)));
typedef float f32x4 __attribute__((ext_vector_type(4)));

__device__ __forceinline__ u16 f2bf(float f) {
  u32 u = __builtin_bit_cast(u32, f);
  u32 r = u + 0x7fffu + ((u >> 16) & 1u);   // round-to-nearest-even
  return (u16)(r >> 16);
}

__device__ __forceinline__ u32 flipf(float f) {
  u32 u = __builtin_bit_cast(u32, f);
  return u ^ ((u32)((int)u >> 31) | 0x80000000u);
}
__device__ __forceinline__ float unflipf(u32 f) {
  u32 m = (~(u32)((int)f >> 31)) | 0x80000000u;
  return __builtin_bit_cast(float, f ^ m);
}

__device__ __forceinline__ void ins3(u64 v, u64& k0, u64& k1, u64& k2) {
  u64 a = k0 < v ? v : k0;
  k0 = k0 < v ? k0 : v;
  u64 bb = k1 < a ? a : k1;
  k1 = k1 < a ? k1 : a;
  k2 = k2 < bb ? k2 : bb;
}

__device__ __forceinline__ void merge3(u64 r0, u64 r1, u64 r2,
                                       u64& k0, u64& k1, u64& k2) {
  u64 t = k0 < r0 ? r0 : k0;
  k0 = k0 < r0 ? k0 : r0;
  u64 u = k1 < r1 ? k1 : r1;
  u64 mtu = t < u ? u : t;
  k1 = t < u ? t : u;
  u64 v = k2 < r2 ? k2 : r2;
  k2 = mtu < v ? mtu : v;
}

__device__ __forceinline__ u64 shfl_xor_u64_w8(u64 v, int mask) {
  u32 lo = (u32)v, hi = (u32)(v >> 32);
  lo = (u32)__shfl_xor((int)lo, mask, 8);
  hi = (u32)__shfl_xor((int)hi, mask, 8);
  return ((u64)hi << 32) | lo;
}

// ---------------------------------------------------------------- W pack
// Pack W1/W2 (f32 row-major [K][N]) into MFMA-B-operand lane order, bf16.
// W1s chunk = ((kt*8 + wd)*4 + ni)*64 + l   (kt<16, wd<8, ni<4, l<64)
//   -> 32768 chunks; l=(g,fr): elements W1[kt*32+g*8+j][wd*64+ni*16+fr]
// W2s chunk = ((kt*8 + wd)*2 + ni)*64 + l   (ni<2) -> 16384 chunks
//   -> elements W2[kt*32+g*8+j][wd*32+ni*16+fr]
// R8 BUG (fixed): W1 split was t<16384 -> kt 8..15 (the x_skip half of W1)
// never written. Now: 49152 threads, split at 32768.
__global__ __launch_bounds__(256) void prep_kernel(
    const float* __restrict__ W1, const float* __restrict__ W2,
    u16* __restrict__ W1s, u16* __restrict__ W2s) {
  const int t = blockIdx.x * 256 + threadIdx.x;   // 192 blocks -> 49152
  if (t < 32768) {
    const int l = t & 63, ni = (t >> 6) & 3, wd = (t >> 8) & 7, kt = t >> 11;
    const int fr = l & 15, g = l >> 4;
    const int n = wd * 64 + ni * 16 + fr;
    u16 o[8];
#pragma unroll
    for (int j = 0; j < 8; ++j)
      o[j] = f2bf(W1[(kt * 32 + g * 8 + j) * CH1 + n]);
    *(uint4*)(W1s + (size_t)t * 8) = *(const uint4*)o;
  } else {
    const int c = t - 32768;                      // 0..16383
    const int l = c & 63, ni = (c >> 6) & 1, wd = (c >> 7) & 7, kt = c >> 10;
    const int fr = l & 15, g = l >> 4;
    const int n = wd * 32 + ni * 16 + fr;
    u16 o[8];
#pragma unroll
    for (int j = 0; j < 8; ++j)
      o[j] = f2bf(W2[(kt * 32 + g * 8 + j) * CH2 + n]);
    *(uint4*)(W2s + (size_t)c * 8) = *(const uint4*)o;
  }
}

// ---------------------------------------------------------------- tail copy
__global__ __launch_bounds__(256) void tail_kernel(
    const float* __restrict__ pos_skip, const int* __restrict__ batch_skip,
    float* __restrict__ out) {
  int t = blockIdx.x * 256 + threadIdx.x;   // 262144 total
  if (t < ROWS * 3) {
    out[POS_OUT_OFF + t] = pos_skip[t];
  } else {
    int u = t - ROWS * 3;
    out[BATCH_OUT_OFF + u] = (float)batch_skip[u];
  }
}

// ---------------------------------------------------------------- cell build
__global__ __launch_bounds__(256) void build_kernel(
    const float* __restrict__ pos, float4* __restrict__ pts4,
    u32* __restrict__ cellCnt, int* __restrict__ cellIdx) {
#pragma clang fp contract(off)
  const int i = blockIdx.x * 256 + threadIdx.x;   // 64 blocks -> 16384
  const float x = pos[i * 3 + 0], y = pos[i * 3 + 1], z = pos[i * 3 + 2];
  pts4[i] = make_float4(x, y, z, (x * x + y * y) + z * z);
  const int b = i >> 12;
  int cx = (int)(x * 8.0f); cx = cx < 0 ? 0 : (cx > 7 ? 7 : cx);
  int cy = (int)(y * 8.0f); cy = cy < 0 ? 0 : (cy > 7 ? 7 : cy);
  int cz = (int)(z * 8.0f); cz = cz < 0 ? 0 : (cz > 7 ? 7 : cz);
  const int c = b * 512 + cz * 64 + cy * 8 + cx;
  const u32 slot = atomicAdd(&cellCnt[c], 1u);
  if (slot < CELL_CAP) cellIdx[c * CELL_CAP + slot] = i;
}

// ---------------------------------------------------------------- query bin
__global__ __launch_bounds__(256) void qbin_kernel(
    const float* __restrict__ pos_skip, u32* __restrict__ qCnt,
    int* __restrict__ qIdx) {
  const int q = blockIdx.x * 256 + threadIdx.x;   // 256 blocks -> 65536
  const int b = q >> 14;
  const float qx = pos_skip[q * 3 + 0];
  const float qy = pos_skip[q * 3 + 1];
  const float qz = pos_skip[q * 3 + 2];
  int cx = (int)(qx * 8.0f); cx = cx < 0 ? 0 : (cx > 7 ? 7 : cx);
  int cy = (int)(qy * 8.0f); cy = cy < 0 ? 0 : (cy > 7 ? 7 : cy);
  int cz = (int)(qz * 8.0f); cz = cz < 0 ? 0 : (cz > 7 ? 7 : cz);
  const int c = b * 512 + cz * 64 + cy * 8 + cx;
  const u32 slot = atomicAdd(&qCnt[c], 1u);
  if (slot < QCAP) qIdx[c * QCAP + slot] = q;
}

// ---------------------------------------------------------------- KNN (k=3)
// (validated R7 structure, unchanged)
__global__ __launch_bounds__(256) void knn_kernel(
    const float4* __restrict__ pts4, const u32* __restrict__ cellCnt,
    const int* __restrict__ cellIdx, const u32* __restrict__ qCnt,
    const int* __restrict__ qIdx, const float* __restrict__ pos_skip,
    int* __restrict__ idx_out, float* __restrict__ w_out) {
#pragma clang fp contract(off)
  __shared__ float4 scand[27 * CELL_CAP];
  __shared__ int    scgi[27 * CELL_CAP];
  __shared__ u32    scnt[27];
  __shared__ int    sbase[27];
  __shared__ u32    nCand;
  const int tid = threadIdx.x;
  const int b = blockIdx.x >> 9;
  const int cell = blockIdx.x & 511;
  const int cz = cell >> 6, cy = (cell >> 3) & 7, cx = cell & 7;
  const int x0 = cx > 0 ? cx - 1 : 0, x1 = cx < 7 ? cx + 1 : 7;
  const int y0 = cy > 0 ? cy - 1 : 0, y1 = cy < 7 ? cy + 1 : 7;
  const int z0 = cz > 0 ? cz - 1 : 0, z1 = cz < 7 ? cz + 1 : 7;
  const int nx = x1 - x0 + 1, ny = y1 - y0 + 1, nz = z1 - z0 + 1;
  const int ncells = nx * ny * nz;
  if (tid == 0) nCand = 0;
  if (tid < ncells) {
    const int lz = tid / (nx * ny);
    const int rem = tid - lz * nx * ny;
    const int ly = rem / nx;
    const int lx = rem - ly * nx;
    const int cg = b * 512 + (z0 + lz) * 64 + (y0 + ly) * 8 + (x0 + lx);
    u32 cnt = cellCnt[cg];
    scnt[tid] = cnt > CELL_CAP ? CELL_CAP : cnt;
    sbase[tid] = cg * CELL_CAP;
  }
  __syncthreads();
  const int slots = ncells * CELL_CAP;
  for (int s = tid; s < slots; s += 256) {
    const int ci = s / CELL_CAP;
    const int sl = s - ci * CELL_CAP;
    if ((u32)sl < scnt[ci]) {
      const int gi = cellIdx[sbase[ci] + sl];
      const float4 p = pts4[gi];
      const u32 d = atomicAdd(&nCand, 1u);
      scand[d] = p;
      scgi[d] = gi;
    }
  }
  __syncthreads();
  const int nC = (int)nCand;
  u32 nq = qCnt[b * 512 + cell];
  if (nq > QCAP) nq = QCAP;
  const int qbase = (b * 512 + cell) * QCAP;
  const int g = tid >> 3;
  const int sub = tid & 7;

  for (int r0q = 0; r0q < (int)nq; r0q += 32) {
    const int qslot = r0q + g;
    if (qslot < (int)nq) {
      const int q = qIdx[qbase + qslot];
      const float qx = pos_skip[q * 3 + 0];
      const float qy = pos_skip[q * 3 + 1];
      const float qz = pos_skip[q * 3 + 2];
      const float q2 = (qx * qx + qy * qy) + qz * qz;
      u64 k0 = ~0ull, k1 = ~0ull, k2 = ~0ull;
      for (int s = sub; s < nC; s += 8) {
        const float4 p = scand[s];
        const float dot = fmaf(qz, p.z, fmaf(qy, p.y, qx * p.x));
        const float tv = (q2 - 2.0f * dot) + p.w;
        const u64 key = ((u64)flipf(tv) << 32) | (u32)scgi[s];
        ins3(key, k0, k1, k2);
      }
#pragma unroll
      for (int mask = 1; mask < 8; mask <<= 1) {
        const u64 r0 = shfl_xor_u64_w8(k0, mask);
        const u64 r1 = shfl_xor_u64_w8(k1, mask);
        const u64 r2 = shfl_xor_u64_w8(k2, mask);
        merge3(r0, r1, r2, k0, k1, k2);
      }
      float m2tv = unflipf((u32)(k2 >> 32));
      if (!(m2tv <= 0.015625f - 1e-5f)) {
        k0 = k1 = k2 = ~0ull;
        const int ex0 = cx > 1 ? cx - 2 : 0, ex1 = cx < 6 ? cx + 2 : 7;
        const int ey0 = cy > 1 ? cy - 2 : 0, ey1 = cy < 6 ? cy + 2 : 7;
        const int ez0 = cz > 1 ? cz - 2 : 0, ez1 = cz < 6 ? cz + 2 : 7;
        for (int zz = ez0; zz <= ez1; ++zz)
          for (int yy = ey0; yy <= ey1; ++yy)
            for (int xx = ex0; xx <= ex1; ++xx) {
              const int cg = b * 512 + zz * 64 + yy * 8 + xx;
              u32 cnt = cellCnt[cg];
              if (cnt > CELL_CAP) cnt = CELL_CAP;
              const int cb = cg * CELL_CAP;
              for (int s = sub; s < (int)cnt; s += 8) {
                const int gi = cellIdx[cb + s];
                const float4 p = pts4[gi];
                const float dot = fmaf(qz, p.z, fmaf(qy, p.y, qx * p.x));
                const float tv = (q2 - 2.0f * dot) + p.w;
                ins3(((u64)flipf(tv) << 32) | (u32)gi, k0, k1, k2);
              }
            }
#pragma unroll
        for (int mask = 1; mask < 8; mask <<= 1) {
          const u64 r0 = shfl_xor_u64_w8(k0, mask);
          const u64 r1 = shfl_xor_u64_w8(k1, mask);
          const u64 r2 = shfl_xor_u64_w8(k2, mask);
          merge3(r0, r1, r2, k0, k1, k2);
        }
        m2tv = unflipf((u32)(k2 >> 32));
        if (!(m2tv <= 0.0625f - 1e-5f)) {
          k0 = k1 = k2 = ~0ull;
          const int base = b * NPTS;
          for (int i = sub; i < NPTS; i += 8) {
            const int gi = base + i;
            const float4 p = pts4[gi];
            const float dot = fmaf(qz, p.z, fmaf(qy, p.y, qx * p.x));
            const float tv = (q2 - 2.0f * dot) + p.w;
            ins3(((u64)flipf(tv) << 32) | (u32)gi, k0, k1, k2);
          }
#pragma unroll
          for (int mask = 1; mask < 8; mask <<= 1) {
            const u64 r0 = shfl_xor_u64_w8(k0, mask);
            const u64 r1 = shfl_xor_u64_w8(k1, mask);
            const u64 r2 = shfl_xor_u64_w8(k2, mask);
            merge3(r0, r1, r2, k0, k1, k2);
          }
        }
      }
      if (sub == 0) {
        const float t0 = unflipf((u32)(k0 >> 32));
        const float t1 = unflipf((u32)(k1 >> 32));
        const float t2 = unflipf((u32)(k2 >> 32));
        const float w0 = 1.0f / fmaxf(t0, 1e-16f);
        const float w1 = 1.0f / fmaxf(t1, 1e-16f);
        const float w2 = 1.0f / fmaxf(t2, 1e-16f);
        const float wsum = (w0 + w1) + w2;
        const float inv = 1.0f / wsum;
        idx_out[q * 3 + 0] = (int)(u32)k0;
        idx_out[q * 3 + 1] = (int)(u32)k1;
        idx_out[q * 3 + 2] = (int)(u32)k2;
        w_out[q * 3 + 0] = w0 * inv;
        w_out[q * 3 + 1] = w1 * inv;
        w_out[q * 3 + 2] = w2 * inv;
      }
    }
  }
}

// ---------------------------------------------------------------- fused MLP
// Block = 64 output rows, 512 threads (8 waves).
// A-build (interp+concat -> LDS bf16, XOR-granule swizzle), then
// phase1 x W1 (register-streamed packed weights, no K-loop barriers),
// relu -> LDS (same buffer), phase2 x W2 -> f32 out.
__global__ __launch_bounds__(512, 2) void fused_mlp_kernel(
    const float* __restrict__ x, const int* __restrict__ idx,
    const float* __restrict__ w, const float* __restrict__ x_skip,
    const u16* __restrict__ W1s, const float* __restrict__ b1,
    const u16* __restrict__ W2s, const float* __restrict__ b2,
    float* __restrict__ out) {
  __shared__ __align__(16) u16 Abuf[64 * 512];   // 64 KB, granule-swizzled
  const int tid = threadIdx.x;
  const int m0 = blockIdx.x * 64;

  // ---- A-build: row = tid>>3 (64 rows), sub = tid&7 (8 x 64-col slices)
  {
    const int row = tid >> 3;
    const int sub = tid & 7;
    const int gr = m0 + row;
    u16* rowp = Abuf + row * 512;
    const int rx = row & 7;
    if (sub < 4) {
      const int i0 = idx[gr * 3 + 0], i1 = idx[gr * 3 + 1], i2 = idx[gr * 3 + 2];
      const float w0 = w[gr * 3 + 0], w1 = w[gr * 3 + 1], w2 = w[gr * 3 + 2];
      const float4* p0 = (const float4*)(x + (size_t)i0 * CIN + sub * 64);
      const float4* p1 = (const float4*)(x + (size_t)i1 * CIN + sub * 64);
      const float4* p2 = (const float4*)(x + (size_t)i2 * CIN + sub * 64);
#pragma unroll
      for (int c = 0; c < 8; ++c) {
        const float4 a0 = p0[c * 2], a1 = p1[c * 2], a2 = p2[c * 2];
        const float4 d0 = p0[c * 2 + 1], d1 = p1[c * 2 + 1], d2 = p2[c * 2 + 1];
        u16 o[8];
        o[0] = f2bf(fmaf(w0, a0.x, fmaf(w1, a1.x, w2 * a2.x)));
        o[1] = f2bf(fmaf(w0, a0.y, fmaf(w1, a1.y, w2 * a2.y)));
        o[2] = f2bf(fmaf(w0, a0.z, fmaf(w1, a1.z, w2 * a2.z)));
        o[3] = f2bf(fmaf(w0, a0.w, fmaf(w1, a1.w, w2 * a2.w)));
        o[4] = f2bf(fmaf(w0, d0.x, fmaf(w1, d1.x, w2 * d2.x)));
        o[5] = f2bf(fmaf(w0, d0.y, fmaf(w1, d1.y, w2 * d2.y)));
        o[6] = f2bf(fmaf(w0, d0.z, fmaf(w1, d1.z, w2 * d2.z)));
        o[7] = f2bf(fmaf(w0, d0.w, fmaf(w1, d1.w, w2 * d2.w)));
        const int vg = sub * 8 + c;
        *(uint4*)(rowp + (vg ^ rx) * 8) = *(const uint4*)o;
      }
    } else {
      const float4* ps = (const float4*)(x_skip + (size_t)gr * CIN + (sub - 4) * 64);
#pragma unroll
      for (int c = 0; c < 8; ++c) {
        const float4 a = ps[c * 2], d = ps[c * 2 + 1];
        u16 o[8];
        o[0] = f2bf(a.x); o[1] = f2bf(a.y); o[2] = f2bf(a.z); o[3] = f2bf(a.w);
        o[4] = f2bf(d.x); o[5] = f2bf(d.y); o[6] = f2bf(d.z); o[7] = f2bf(d.w);
        const int vg = 32 + (sub - 4) * 8 + c;
        *(uint4*)(rowp + (vg ^ rx) * 8) = *(const uint4*)o;
      }
    }
  }
  __syncthreads();

  const int wid = tid >> 6;
  const int lane = tid & 63;
  const int fr = lane & 15;
  const int g = lane >> 4;
  const int frx = fr & 7;

  // ---- phase 1: H[64][512] = A[64][512] @ W1 (wave: m64 x n64)
  f32x4 acc[4][4];
#pragma unroll
  for (int mi = 0; mi < 4; mi++)
#pragma unroll
    for (int ni = 0; ni < 4; ni++) acc[mi][ni] = (f32x4){0.f, 0.f, 0.f, 0.f};

  {
    const u16* B1 = W1s + wid * 2048 + lane * 8;   // + kt*16384 + ni*512
    bf16x8 bf[2][4];
#pragma unroll
    for (int ni = 0; ni < 4; ni++)
      bf[0][ni] = *(const bf16x8*)(B1 + ni * 512);
    for (int kt = 0; kt < 16; ++kt) {
      const int cur = kt & 1;
      if (kt < 15) {
        const u16* nb = B1 + (kt + 1) * 16384;
#pragma unroll
        for (int ni = 0; ni < 4; ni++)
          bf[cur ^ 1][ni] = *(const bf16x8*)(nb + ni * 512);
      }
      bf16x8 af[4];
#pragma unroll
      for (int mi = 0; mi < 4; mi++)
        af[mi] = *(const bf16x8*)&Abuf[(mi * 16 + fr) * 512 +
                                       (((kt * 4 + g) ^ frx) * 8)];
#pragma unroll
      for (int mi = 0; mi < 4; mi++)
#pragma unroll
        for (int ni = 0; ni < 4; ni++)
          acc[mi][ni] = __builtin_amdgcn_mfma_f32_16x16x32_bf16(
              af[mi], bf[cur][ni], acc[mi][ni], 0, 0, 0);
    }
  }
  __syncthreads();                 // all Abuf reads complete

  // ---- relu + bias -> bf16 back into Abuf (as H, same swizzle)
  {
    const int wn = wid * 64;
#pragma unroll
    for (int ni = 0; ni < 4; ni++) {
      const int n = wn + ni * 16 + fr;
      const float bb = b1[n];
      const int vg = n >> 3;
      const int nlow = n & 7;
#pragma unroll
      for (int mi = 0; mi < 4; mi++) {
#pragma unroll
        for (int r = 0; r < 4; r++) {
          const int m = mi * 16 + g * 4 + r;
          const float v = fmaxf(acc[mi][ni][r] + bb, 0.f);
          Abuf[m * 512 + (vg ^ (m & 7)) * 8 + nlow] = f2bf(v);
        }
      }
    }
  }
  __syncthreads();                 // H complete

  // ---- phase 2: C[64][256] = H[64][512] @ W2 (wave: m64 x n32)
  f32x4 acc2[4][2];
#pragma unroll
  for (int mi = 0; mi < 4; mi++)
#pragma unroll
    for (int ni = 0; ni < 2; ni++) acc2[mi][ni] = (f32x4){0.f, 0.f, 0.f, 0.f};

  {
    const u16* B2 = W2s + wid * 1024 + lane * 8;   // + kt*8192 + ni*512
    bf16x8 bf[2][2];
#pragma unroll
    for (int ni = 0; ni < 2; ni++)
      bf[0][ni] = *(const bf16x8*)(B2 + ni * 512);
    for (int kt = 0; kt < 16; ++kt) {
      const int cur = kt & 1;
      if (kt < 15) {
        const u16* nb = B2 + (kt + 1) * 8192;
#pragma unroll
        for (int ni = 0; ni < 2; ni++)
          bf[cur ^ 1][ni] = *(const bf16x8*)(nb + ni * 512);
      }
      bf16x8 af[4];
#pragma unroll
      for (int mi = 0; mi < 4; mi++)
        af[mi] = *(const bf16x8*)&Abuf[(mi * 16 + fr) * 512 +
                                       (((kt * 4 + g) ^ frx) * 8)];
#pragma unroll
      for (int mi = 0; mi < 4; mi++)
#pragma unroll
        for (int ni = 0; ni < 2; ni++)
          acc2[mi][ni] = __builtin_amdgcn_mfma_f32_16x16x32_bf16(
              af[mi], bf[cur][ni], acc2[mi][ni], 0, 0, 0);
    }
  }

  // ---- epilogue: relu + bias2 -> f32 out
#pragma unroll
  for (int ni = 0; ni < 2; ni++) {
    const int col = wid * 32 + ni * 16 + fr;
    const float bb = b2[col];
#pragma unroll
    for (int mi = 0; mi < 4; mi++) {
#pragma unroll
      for (int r = 0; r < 4; r++) {
        const int rowg = m0 + mi * 16 + g * 4 + r;
        out[(size_t)rowg * CH2 + col] = fmaxf(acc2[mi][ni][r] + bb, 0.f);
      }
    }
  }
}

// ---------------------------------------------------------------- launch
extern "C" void kernel_launch(void* const* d_in, const int* in_sizes, int n_in,
                              void* d_out, int out_size, void* d_ws, size_t ws_size,
                              hipStream_t stream) {
  const float* x        = (const float*)d_in[0];
  const float* pos      = (const float*)d_in[1];
  const float* x_skip   = (const float*)d_in[3];
  const float* pos_skip = (const float*)d_in[4];
  const int*   batch_sk = (const int*)d_in[5];
  const float* W1       = (const float*)d_in[6];
  const float* b1       = (const float*)d_in[7];
  const float* W2       = (const float*)d_in[8];
  const float* b2       = (const float*)d_in[9];
  float* out = (float*)d_out;

  char* ws = (char*)d_ws;
  u16*    W1s     = (u16*)(ws);                 // 524288 B
  u16*    W2s     = (u16*)(ws + 524288);        // 262144 B
  int*    idxb    = (int*)(ws + 786432);        // 786432 B
  float*  wb      = (float*)(ws + 1572864);     // 786432 B
  float4* pts4    = (float4*)(ws + 2359296);    // 262144 B
  u32*    cellCnt = (u32*)(ws + 2621440);       // 8192 B
  u32*    qCnt    = (u32*)(ws + 2629632);       // 8192 B
  int*    cellIdx = (int*)(ws + 2637824);       // 327680 B
  int*    qIdx    = (int*)(ws + 2965504);       // 786432 B
  // total 3,751,936 B

  hipMemsetAsync(cellCnt, 0, 16384, stream);    // cellCnt + qCnt
  prep_kernel<<<dim3(192), dim3(256), 0, stream>>>(W1, W2, W1s, W2s);
  tail_kernel<<<dim3(1024), dim3(256), 0, stream>>>(pos_skip, batch_sk, out);
  build_kernel<<<dim3(64), dim3(256), 0, stream>>>(pos, pts4, cellCnt, cellIdx);
  qbin_kernel<<<dim3(256), dim3(256), 0, stream>>>(pos_skip, qCnt, qIdx);
  knn_kernel<<<dim3(2048), dim3(256), 0, stream>>>(pts4, cellCnt, cellIdx,
                                                   qCnt, qIdx, pos_skip,
                                                   idxb, wb);
  fused_mlp_kernel<<<dim3(1024), dim3(512), 0, stream>>>(
      x, idxb, wb, x_skip, W1s, b1, W2s, b2, out);
}